// Round 1
// baseline (253.069 us; speedup 1.0000x reference)
//
#include <hip/hip_runtime.h>
#include <hip/hip_fp16.h>

namespace {

constexpr int T_STEPS = 256;
constexpr int HD = 50;    // hidden size
constexpr int HP = 64;    // padded hidden
constexpr int KST = 88;   // h-buf row stride in fp16 elems
constexpr int KSTS = 72;  // weight staging stride
constexpr int BT = 16;    // batch tile per block
constexpr int NTHR = 192; // R12: 3 waves — ONE wave per layer, 4 M-tiles each
constexpr int XST = 34;   // xls row stride in floats
constexpr int LAY_SH = BT * KST;     // shorts per (slot, layer)
constexpr int SLOT_SH = 3 * LAY_SH;  // shorts per ring slot

typedef __attribute__((ext_vector_type(8))) _Float16 f16x8;
typedef __attribute__((ext_vector_type(4))) float f32x4;

__device__ __forceinline__ unsigned short f2h(float x) {
  __half h = __float2half(x);  // RNE
  return *reinterpret_cast<unsigned short*>(&h);
}
__device__ __forceinline__ float h2f(unsigned short u) {
  __half h;
  *reinterpret_cast<unsigned short*>(&h) = u;
  return __half2float(h);
}

#define MFMA16 __builtin_amdgcn_mfma_f32_16x16x32_f16

// Raw workgroup barrier WITHOUT the lgkmcnt(0) drain that __syncthreads emits.
// Safe: DS ops enter the CU's LDS pipe at ISSUE in program order; consumer
// reads issue only after barrier release, i.e. after producers' writes are
// enqueued; per-bank FIFO processing gives RAW visibility. (Validated on HW
// by the R11 kernel.)
__device__ __forceinline__ void barrier_nodrain() {
  asm volatile("s_barrier" ::: "memory");
}

// R12 restructure: 12 waves (layer x M-tile) -> 3 waves (one per layer).
// Each wave owns all 4 M-tiles of its layer, so the B-fragments (h) are read
// from LDS ONCE per step and amortized over 16 MFMAs (was: 4 waves each
// re-reading full h for 4 MFMAs). Per-step LDS traffic 46KB -> 16KB.
// Self-h B-frags for step s+1 are read PRE-barrier right after the wave's own
// write (same-wave DS ordering; no sync needed); cross keeps the 1-step
// prefetch. Post-barrier the wave starts MFMA immediately, operands in regs.
// Ring slots / diagonal offsets (0/2/4) / schedule identical to R11.
__global__ __launch_bounds__(NTHR, 1) void rnn3_kernel(
    const float* __restrict__ x,
    const float* __restrict__ Wih1, const float* __restrict__ Whh1,
    const float* __restrict__ bih1, const float* __restrict__ bhh1,
    const float* __restrict__ Wih2, const float* __restrict__ Whh2,
    const float* __restrict__ bih2, const float* __restrict__ bhh2,
    const float* __restrict__ Wih3, const float* __restrict__ Whh3,
    const float* __restrict__ bih3, const float* __restrict__ bhh3,
    const float* __restrict__ fcw, const float* __restrict__ fcb,
    float* __restrict__ out) {
  __shared__ unsigned short hbuf[3 * SLOT_SH];  // [ring][layer][b*KST+k], fp16 bits
  __shared__ float xls[T_STEPS][XST];           // staged x
  __shared__ unsigned short scr[HP * KSTS];     // weight staging (fp16)

  const int tid = threadIdx.x;
  const int myL = tid >> 6;      // wave = layer 0..2
  const int lane = tid & 63;
  const int quad = lane >> 4;
  const int l15 = lane & 15;
  const int b0 = blockIdx.x * BT;

  // zero all 3 ring slots (initial h=0 and the k>=HD pad), vectorized
  {
    uint4* hz = reinterpret_cast<uint4*>(hbuf);
    const int n = 3 * SLOT_SH * 2 / 16;  // 16B chunks (SLOT_SH*2 % 16 == 0)
    for (int i = tid; i < n; i += NTHR) hz[i] = make_uint4(0u, 0u, 0u, 0u);
  }
  // stage x -> LDS
  for (int idx = tid; idx < BT * T_STEPS; idx += NTHR) {
    int b = idx >> 8, t = idx & 255;
    float2 v = *reinterpret_cast<const float2*>(x + (size_t)(b0 + b) * (T_STEPS * 2) + 2 * t);
    xls[t][2 * b] = v.x;
    xls[t][2 * b + 1] = v.y;
  }

  // ---- stage the five 50x50 matrices as fp16; each wave grabs 4 M-tiles ----
  const float* mats[5] = {Whh1, Wih2, Whh2, Wih3, Whh3};
  constexpr int matL[5] = {0, 1, 1, 2, 2};
  constexpr int matS[5] = {0, 0, 1, 0, 1};  // slot0 = cross (self for L0), slot1 = self
  f16x8 wA[2][4][2];  // [slot][M-tile][kstep]
#pragma unroll
  for (int sl = 0; sl < 2; ++sl)
#pragma unroll
    for (int m = 0; m < 4; ++m)
#pragma unroll
      for (int ks = 0; ks < 2; ++ks) wA[sl][m][ks] = f16x8(0);

#pragma unroll
  for (int mm = 0; mm < 5; ++mm) {
    __syncthreads();
    const float* W = mats[mm];
    for (int idx = tid; idx < HP * HP; idx += NTHR) {
      int i = idx >> 6, k = idx & 63;
      float v = (i < HD && k < HD) ? W[i * HD + k] : 0.0f;
      scr[i * KSTS + k] = f2h(v);
    }
    __syncthreads();
    if (myL == matL[mm]) {
      const int sl = matS[mm];
#pragma unroll
      for (int m = 0; m < 4; ++m) {
        const unsigned short* ph = &scr[(16 * m + l15) * KSTS + 8 * quad];
        wA[sl][m][0] = *reinterpret_cast<const f16x8*>(ph);
        wA[sl][m][1] = *reinterpret_cast<const f16x8*>(ph + 32);
      }
    }
  }

  // per-lane C-row constants, per M-tile
  const float* bi = (myL == 0) ? bih1 : (myL == 1) ? bih2 : bih3;
  const float* bh = (myL == 0) ? bhh1 : (myL == 1) ? bhh2 : bhh3;
  f32x4 bsv[4];
  float wx0[4][4], wx1[4][4];
#pragma unroll
  for (int m = 0; m < 4; ++m)
#pragma unroll
    for (int r = 0; r < 4; ++r) {
      int i = 16 * m + 4 * quad + r;
      bool v = i < HD;
      bsv[m][r] = v ? (bi[i] + bh[i]) : 0.0f;
      wx0[m][r] = (v && myL == 0) ? Wih1[i * 2 + 0] : 0.0f;
      wx1[m][r] = (v && myL == 0) ? Wih1[i * 2 + 1] : 0.0f;
    }

  const int ldsOff = l15 * KST + 8 * quad;
  const unsigned short* sbase = hbuf + myL * LAY_SH + ldsOff;
  const unsigned short* cbase = hbuf + ((myL > 0) ? myL - 1 : 0) * LAY_SH + ldsOff;
  unsigned short* wb = hbuf + myL * LAY_SH + l15 * KST + 4 * quad;

  // wave-persistent operand registers
  f16x8 bS0 = f16x8(0), bS1 = f16x8(0);   // self B-frags for CURRENT step (h[-1]=0)
  f16x8 pfC0 = f16x8(0), pfC1 = f16x8(0); // cross B-frags for CURRENT step
  float2 xpf;

  __syncthreads();
  xpf = *reinterpret_cast<const float2*>(&xls[0][2 * l15]);

  // operand reads for the NEXT step; issued pre-barrier.
  // self: slot wr = s%3 (just written by THIS wave -> same-wave DS order, safe)
  // cross: slot rd = (s-1)%3 (written by producer before previous barrier)
  auto prefetch = [&](int s, int wr, int rd) {
    bS0 = *reinterpret_cast<const f16x8*>(sbase + wr * SLOT_SH);
    bS1 = *reinterpret_cast<const f16x8*>(sbase + wr * SLOT_SH + 32);
    if (myL > 0) {
      pfC0 = *reinterpret_cast<const f16x8*>(cbase + rd * SLOT_SH);
      pfC1 = *reinterpret_cast<const f16x8*>(cbase + rd * SLOT_SH + 32);
    } else {
      xpf = *reinterpret_cast<const float2*>(&xls[(s + 1) & 255][2 * l15]);
    }
  };

  // ---- compute core for one diagonal step ----
  auto core = [&](int s, int wr, int rd) {
    f32x4 cm[4];
    if (myL == 0) {
#pragma unroll
      for (int m = 0; m < 4; ++m) {
        f32x4 ci;
#pragma unroll
        for (int r = 0; r < 4; ++r)
          ci[r] = fmaf(wx1[m][r], xpf.y, fmaf(wx0[m][r], xpf.x, bsv[m][r]));
        f32x4 c = MFMA16(wA[0][m][0], bS0, ci, 0, 0, 0);
        cm[m] = MFMA16(wA[0][m][1], bS1, c, 0, 0, 0);
      }
    } else {
#pragma unroll
      for (int m = 0; m < 4; ++m) {
        f32x4 c = MFMA16(wA[0][m][0], pfC0, bsv[m], 0, 0, 0);
        c = MFMA16(wA[0][m][1], pfC1, c, 0, 0, 0);
        c = MFMA16(wA[1][m][0], bS0, c, 0, 0, 0);
        cm[m] = MFMA16(wA[1][m][1], bS1, c, 0, 0, 0);
      }
    }
    // batched tanh: ONE rcp per 4 values; clamp keeps product < f32-max
#pragma unroll
    for (int m = 0; m < 3; ++m) {
      float d[4];
#pragma unroll
      for (int r = 0; r < 4; ++r) {
        float xr = __builtin_amdgcn_fmed3f(cm[m][r], -11.0f, 11.0f);
        d[r] = __expf(2.0f * xr) + 1.0f;
      }
      float p01 = d[0] * d[1], p23 = d[2] * d[3];
      float rp = __builtin_amdgcn_rcpf(p01 * p23);
      float q01 = rp * p23, q23 = rp * p01;
      unsigned short t0 = f2h(fmaf(-2.0f, q01 * d[1], 1.0f));
      unsigned short t1 = f2h(fmaf(-2.0f, q01 * d[0], 1.0f));
      unsigned short t2 = f2h(fmaf(-2.0f, q23 * d[3], 1.0f));
      unsigned short t3 = f2h(fmaf(-2.0f, q23 * d[2], 1.0f));
      *reinterpret_cast<uint2*>(wb + wr * SLOT_SH + 16 * m) =
          make_uint2((unsigned)t0 | ((unsigned)t1 << 16),
                     (unsigned)t2 | ((unsigned)t3 << 16));
    }
    {  // m=3: rows 48+4q+{0,1}; rows >=50 are exactly 0 (zero A-rows + zero
       // bias -> c=0 -> tanh=0), so write literal 0 for the second word and
       // skip half the tanh work.
      float x0 = __builtin_amdgcn_fmed3f(cm[3][0], -11.0f, 11.0f);
      float x1 = __builtin_amdgcn_fmed3f(cm[3][1], -11.0f, 11.0f);
      float d0 = __expf(2.0f * x0) + 1.0f;
      float d1 = __expf(2.0f * x1) + 1.0f;
      float rp = __builtin_amdgcn_rcpf(d0 * d1);
      unsigned short t0 = f2h(fmaf(-2.0f, rp * d1, 1.0f));
      unsigned short t1 = f2h(fmaf(-2.0f, rp * d0, 1.0f));
      *reinterpret_cast<uint2*>(wb + wr * SLOT_SH + 48) =
          make_uint2((unsigned)t0 | ((unsigned)t1 << 16), 0u);
    }
    prefetch(s, wr, rd);  // AFTER write: self slot wr now holds h[s]
  };

  auto actOf = [&](int s) {
    return (myL == 0) ? (s < T_STEPS)
         : (myL == 1) ? (s >= 2 && s < T_STEPS + 2)
                      : (s >= 4);
  };

  // barrier-mode step (prologue/epilogue): full __syncthreads for safety.
  // Inactive waves must still run prefetch to keep operand regs current.
  auto stepB = [&](int s, int wr, int rd, bool act) {
    if (act) core(s, wr, rd);
    else prefetch(s, wr, rd);
    __syncthreads();
  };

  // prologue s=0..3
  for (int s = 0; s < 4; ++s) stepB(s, s % 3, (s + 2) % 3, actOf(s));
  // steady s=4..255: all waves active; literal ring slots; NO-DRAIN barrier
  for (int sb = 4; sb < 256; sb += 3) {
    core(sb + 0, 1, 0); barrier_nodrain();
    core(sb + 1, 2, 1); barrier_nodrain();
    core(sb + 2, 0, 2); barrier_nodrain();
  }
  __syncthreads();  // re-establish full ordering before act-gated epilogue
  // epilogue s=256..259
  for (int s = 256; s < 260; ++s) stepB(s, s % 3, (s + 2) % 3, actOf(s));

  // ---- fc epilogue: h3_255 written at s=259 -> slot 259%3 = 1 ----
  if (tid < BT * 2) {
    int b = tid >> 1, o = tid & 1;
    const unsigned short* h3 = hbuf + 1 * SLOT_SH + 2 * LAY_SH + b * KST;
    float acc = fcb[o];
    for (int i = 0; i < HD; ++i) acc += fcw[o * HD + i] * h2f(h3[i]);
    out[(size_t)(b0 + b) * 2 + o] = acc;
  }
}

}  // namespace

extern "C" void kernel_launch(void* const* d_in, const int* in_sizes, int n_in,
                              void* d_out, int out_size, void* d_ws, size_t ws_size,
                              hipStream_t stream) {
  const float* x = (const float*)d_in[0];
  const float* Wih1 = (const float*)d_in[1];
  const float* Whh1 = (const float*)d_in[2];
  const float* bih1 = (const float*)d_in[3];
  const float* bhh1 = (const float*)d_in[4];
  const float* Wih2 = (const float*)d_in[5];
  const float* Whh2 = (const float*)d_in[6];
  const float* bih2 = (const float*)d_in[7];
  const float* bhh2 = (const float*)d_in[8];
  const float* Wih3 = (const float*)d_in[9];
  const float* Whh3 = (const float*)d_in[10];
  const float* bih3 = (const float*)d_in[11];
  const float* bhh3 = (const float*)d_in[12];
  const float* fcw = (const float*)d_in[13];
  const float* fcb = (const float*)d_in[14];

  rnn3_kernel<<<4096 / BT, NTHR, 0, stream>>>(x, Wih1, Whh1, bih1, bhh1,
                                              Wih2, Whh2, bih2, bhh2,
                                              Wih3, Whh3, bih3, bhh3,
                                              fcw, fcb, (float*)d_out);
}

// Round 2
// 192.236 us; speedup vs baseline: 1.3165x; 1.3165x over previous
//
#include <hip/hip_runtime.h>
#include <hip/hip_fp16.h>

namespace {

constexpr int T_STEPS = 256;
constexpr int HD = 50;    // hidden size
constexpr int HP = 64;    // padded hidden
constexpr int KST = 88;   // h-buf row stride in fp16 elems
constexpr int KSTS = 72;  // weight staging stride
constexpr int BT = 16;    // batch tile per block
constexpr int NTHR = 768; // 12 waves: (layer, M-tile) — measured-best config
constexpr int XST = 34;   // xls row stride in floats
constexpr int LAY_SH = BT * KST;     // shorts per (slot, layer)
constexpr int SLOT_SH = 3 * LAY_SH;  // shorts per ring slot

typedef __attribute__((ext_vector_type(8))) _Float16 f16x8;
typedef __attribute__((ext_vector_type(4))) float f32x4;

__device__ __forceinline__ unsigned short f2h(float x) {
  __half h = __float2half(x);  // RNE
  return *reinterpret_cast<unsigned short*>(&h);
}
__device__ __forceinline__ float h2f(unsigned short u) {
  __half h;
  *reinterpret_cast<unsigned short*>(&h) = u;
  return __half2float(h);
}

#define MFMA16 __builtin_amdgcn_mfma_f32_16x16x32_f16

// Raw workgroup barrier WITHOUT the lgkmcnt(0) drain that __syncthreads emits.
// Safe: DS ops enter the CU's LDS pipe at ISSUE in program order; consumer
// reads issue only after barrier release, i.e. after producers' writes are
// enqueued; per-bank FIFO processing gives RAW visibility. (HW-validated by
// the R11 kernel.)
__device__ __forceinline__ void barrier_nodrain() {
  asm volatile("s_barrier" ::: "memory");
}

// R13: R11's 12-wave (layer x M-tile) structure, de-convoyed.
// R12 post-mortem: 3 waves = latency-exposed serial chain (181us). R11's win
// was 3 waves/SIMD of stall hiding; its cost was a 44-wave-read LDS burst at
// the top of every step (post-barrier) while VALU idles, then a VALU tanh
// burst while LDS idles. R13 moves the only pre-barrier-legal reads — the
// cross-layer prefetch (producer wrote before the PREVIOUS barrier) and the
// static xls read — to the END of core, under the tanh phase. Post-barrier
// burst: 44 -> 24 reads, and L1/L2 open with 2 register-resident cross MFMAs
// that cover the self-read latency. wv==3 waves: rows >=50 are structurally
// zero -> 2-value tanh, quad0-only write (pad rows keep their init zeros).
__global__ __launch_bounds__(NTHR, 3) void rnn3_kernel(
    const float* __restrict__ x,
    const float* __restrict__ Wih1, const float* __restrict__ Whh1,
    const float* __restrict__ bih1, const float* __restrict__ bhh1,
    const float* __restrict__ Wih2, const float* __restrict__ Whh2,
    const float* __restrict__ bih2, const float* __restrict__ bhh2,
    const float* __restrict__ Wih3, const float* __restrict__ Whh3,
    const float* __restrict__ bih3, const float* __restrict__ bhh3,
    const float* __restrict__ fcw, const float* __restrict__ fcb,
    float* __restrict__ out) {
  __shared__ unsigned short hbuf[3 * SLOT_SH];  // [ring][layer][b*KST+k], fp16 bits
  __shared__ float xls[T_STEPS][XST];           // staged x
  __shared__ unsigned short scr[HP * KSTS];     // weight staging (fp16)

  const int tid = threadIdx.x;
  const int w = tid >> 6;
  const int myL = w >> 2;        // layer 0..2
  const int wv = w & 3;          // M-tile
  const int lane = tid & 63;
  const int quad = lane >> 4;
  const int l15 = lane & 15;
  const int b0 = blockIdx.x * BT;

  // zero all 3 ring slots (initial h=0 and the k>=HD pad)
  {
    unsigned int* hz = reinterpret_cast<unsigned int*>(hbuf);
    const int n = 3 * SLOT_SH / 2;
    for (int i = tid; i < n; i += NTHR) hz[i] = 0u;
  }
  // stage x -> LDS
  for (int idx = tid; idx < BT * T_STEPS; idx += NTHR) {
    int b = idx >> 8, t = idx & 255;
    float2 v = *reinterpret_cast<const float2*>(x + (size_t)(b0 + b) * (T_STEPS * 2) + 2 * t);
    xls[t][2 * b] = v.x;
    xls[t][2 * b + 1] = v.y;
  }

  // ---- stage the five 50x50 matrices as fp16 ----
  const float* mats[5] = {Whh1, Wih2, Whh2, Wih3, Whh3};
  constexpr int matL[5] = {0, 1, 1, 2, 2};
  constexpr int matS[5] = {0, 0, 1, 0, 1};  // slot0 = cross (self for L0), slot1 = self
  f16x8 wA[2][2];  // [slot][kstep]
#pragma unroll
  for (int sl = 0; sl < 2; ++sl)
#pragma unroll
    for (int ks = 0; ks < 2; ++ks) wA[sl][ks] = f16x8(0);

  const int arow = 16 * wv + l15;
#pragma unroll
  for (int m = 0; m < 5; ++m) {
    __syncthreads();
    const float* W = mats[m];
    for (int idx = tid; idx < HP * HP; idx += NTHR) {
      int i = idx >> 6, k = idx & 63;
      float v = (i < HD && k < HD) ? W[i * HD + k] : 0.0f;
      scr[i * KSTS + k] = f2h(v);
    }
    __syncthreads();
    if (myL == matL[m]) {
      const int sl = matS[m];
      const unsigned short* ph = &scr[arow * KSTS + 8 * quad];
      wA[sl][0] = *reinterpret_cast<const f16x8*>(ph);
      wA[sl][1] = *reinterpret_cast<const f16x8*>(ph + 32);
    }
  }

  // per-lane C-row constants
  const int ic = 16 * wv + 4 * quad;
  const float* bi = (myL == 0) ? bih1 : (myL == 1) ? bih2 : bih3;
  const float* bh = (myL == 0) ? bhh1 : (myL == 1) ? bhh2 : bhh3;
  float wx0[4], wx1[4];
  f32x4 bsv;
#pragma unroll
  for (int r = 0; r < 4; ++r) {
    int i = ic + r;
    bool v = i < HD;
    bsv[r] = v ? (bi[i] + bh[i]) : 0.0f;
    wx0[r] = (v && myL == 0) ? Wih1[i * 2 + 0] : 0.0f;
    wx1[r] = (v && myL == 0) ? Wih1[i * 2 + 1] : 0.0f;
  }

  const int selfBuf = myL;
  const int crossBuf = (myL > 0) ? myL - 1 : 0;
  const int ldsOff = l15 * KST + 8 * quad;

  const unsigned short* sbase = hbuf + selfBuf * LAY_SH + ldsOff;
  const unsigned short* cbase = hbuf + crossBuf * LAY_SH + ldsOff;
  unsigned short* wbase = hbuf + myL * LAY_SH + l15 * KST + ic;

  f16x8 pfC0 = f16x8(0), pfC1 = f16x8(0);  // cross B-frags for CURRENT step
  float2 xpf;                              // x for CURRENT step (L0)

  __syncthreads();
  xpf = *reinterpret_cast<const float2*>(&xls[0][2 * l15]);

  // ---- compute core for one diagonal step ----
  // Self reads stay post-barrier (sibling waves wrote them THIS barrier
  // interval). Cross/x prefetch for step s+1 moved to the END: slot rd
  // holds upstream h[s-1], written before the PREVIOUS barrier -> no race,
  // and the reads land in the tanh phase when the LDS pipe is idle.
  auto core = [&](int s, int wr, int rd) {
    f16x8 bS0 = *reinterpret_cast<const f16x8*>(sbase + rd * SLOT_SH);
    f16x8 bS1 = *reinterpret_cast<const f16x8*>(sbase + rd * SLOT_SH + 32);
    f32x4 c;
    if (myL == 0) {
      f32x4 ci;
#pragma unroll
      for (int r = 0; r < 4; ++r) ci[r] = fmaf(wx1[r], xpf.y, fmaf(wx0[r], xpf.x, bsv[r]));
      c = MFMA16(wA[0][0], bS0, ci, 0, 0, 0);
      c = MFMA16(wA[0][1], bS1, c, 0, 0, 0);
    } else {
      // cross MFMAs first: operands already in registers (prefetched), run
      // while the self ds_reads above are still in flight.
      c = MFMA16(wA[0][0], pfC0, bsv, 0, 0, 0);
      c = MFMA16(wA[0][1], pfC1, c, 0, 0, 0);
      c = MFMA16(wA[1][0], bS0, c, 0, 0, 0);
      c = MFMA16(wA[1][1], bS1, c, 0, 0, 0);
    }
    if (wv != 3) {
      // batched tanh: ONE rcp for 4 values; clamp keeps product < f32-max
      float d[4];
#pragma unroll
      for (int r = 0; r < 4; ++r) {
        float xr = __builtin_amdgcn_fmed3f(c[r], -11.0f, 11.0f);
        d[r] = __expf(2.0f * xr) + 1.0f;
      }
      float p01 = d[0] * d[1], p23 = d[2] * d[3];
      float rp = __builtin_amdgcn_rcpf(p01 * p23);
      float q01 = rp * p23, q23 = rp * p01;
      float iv[4] = {q01 * d[1], q01 * d[0], q23 * d[3], q23 * d[2]};
      unsigned short ht[4];
#pragma unroll
      for (int r = 0; r < 4; ++r) ht[r] = f2h(fmaf(-2.0f, iv[r], 1.0f));
      unsigned int h01 = (unsigned int)ht[0] | ((unsigned int)ht[1] << 16);
      unsigned int h23 = (unsigned int)ht[2] | ((unsigned int)ht[3] << 16);
      *reinterpret_cast<uint2*>(wbase + wr * SLOT_SH) = make_uint2(h01, h23);
    } else {
      // rows 48..63: only 48,49 (quad0, r0/r1) are live; rest are exactly 0
      // (zero A-rows + zero bias) and keep their one-time init zeros.
      float x0 = __builtin_amdgcn_fmed3f(c[0], -11.0f, 11.0f);
      float x1 = __builtin_amdgcn_fmed3f(c[1], -11.0f, 11.0f);
      float d0 = __expf(2.0f * x0) + 1.0f;
      float d1 = __expf(2.0f * x1) + 1.0f;
      float rp = __builtin_amdgcn_rcpf(d0 * d1);
      unsigned short t0 = f2h(fmaf(-2.0f, rp * d1, 1.0f));
      unsigned short t1 = f2h(fmaf(-2.0f, rp * d0, 1.0f));
      if (quad == 0) {
        *reinterpret_cast<uint2*>(wbase + wr * SLOT_SH) =
            make_uint2((unsigned)t0 | ((unsigned)t1 << 16), 0u);
      }
    }
    // end-of-core prefetch for step s+1 (slot rd == (s-1)%3: safe pre-barrier)
    if (myL > 0) {
      pfC0 = *reinterpret_cast<const f16x8*>(cbase + rd * SLOT_SH);
      pfC1 = *reinterpret_cast<const f16x8*>(cbase + rd * SLOT_SH + 32);
    } else {
      xpf = *reinterpret_cast<const float2*>(&xls[(s + 1) & 255][2 * l15]);
    }
  };

  auto actOf = [&](int s) {
    return (myL == 0) ? (s < T_STEPS)
         : (myL == 1) ? (s >= 2 && s < T_STEPS + 2)
                      : (s >= 4);
  };

  // barrier-mode step (prologue/epilogue): full __syncthreads for safety.
  // Inactive waves still prefetch to keep pfC current for their first step.
  auto stepB = [&](int s, int wr, int rd, bool act) {
    if (act) {
      core(s, wr, rd);
    } else if (myL > 0) {
      pfC0 = *reinterpret_cast<const f16x8*>(cbase + rd * SLOT_SH);
      pfC1 = *reinterpret_cast<const f16x8*>(cbase + rd * SLOT_SH + 32);
    }
    __syncthreads();
  };

  // prologue s=0..3
  for (int s = 0; s < 4; ++s) stepB(s, s % 3, (s + 2) % 3, actOf(s));
  // steady s=4..255: all waves active; literal ring slots; NO-DRAIN barrier
  for (int sb = 4; sb < 256; sb += 3) {
    core(sb + 0, 1, 0); barrier_nodrain();
    core(sb + 1, 2, 1); barrier_nodrain();
    core(sb + 2, 0, 2); barrier_nodrain();
  }
  __syncthreads();  // re-establish full ordering before act-gated epilogue
  // epilogue s=256..259
  for (int s = 256; s < 260; ++s) stepB(s, s % 3, (s + 2) % 3, actOf(s));

  // ---- fc epilogue: h3_255 written at s=259 -> slot 259%3 = 1 ----
  if (tid < BT * 2) {
    int b = tid >> 1, o = tid & 1;
    const unsigned short* h3 = hbuf + 1 * SLOT_SH + 2 * LAY_SH + b * KST;
    float acc = fcb[o];
    for (int i = 0; i < HD; ++i) acc += fcw[o * HD + i] * h2f(h3[i]);
    out[(size_t)(b0 + b) * 2 + o] = acc;
  }
}

}  // namespace

extern "C" void kernel_launch(void* const* d_in, const int* in_sizes, int n_in,
                              void* d_out, int out_size, void* d_ws, size_t ws_size,
                              hipStream_t stream) {
  const float* x = (const float*)d_in[0];
  const float* Wih1 = (const float*)d_in[1];
  const float* Whh1 = (const float*)d_in[2];
  const float* bih1 = (const float*)d_in[3];
  const float* bhh1 = (const float*)d_in[4];
  const float* Wih2 = (const float*)d_in[5];
  const float* Whh2 = (const float*)d_in[6];
  const float* bih2 = (const float*)d_in[7];
  const float* bhh2 = (const float*)d_in[8];
  const float* Wih3 = (const float*)d_in[9];
  const float* Whh3 = (const float*)d_in[10];
  const float* bih3 = (const float*)d_in[11];
  const float* bhh3 = (const float*)d_in[12];
  const float* fcw = (const float*)d_in[13];
  const float* fcb = (const float*)d_in[14];

  rnn3_kernel<<<4096 / BT, NTHR, 0, stream>>>(x, Wih1, Whh1, bih1, bhh1,
                                              Wih2, Whh2, bih2, bhh2,
                                              Wih3, Whh3, bih3, bhh3,
                                              fcw, fcb, (float*)d_out);
}